// Round 2
// baseline (283.614 us; speedup 1.0000x reference)
//
#include <hip/hip_runtime.h>

// ---------------- types / helpers ----------------
typedef float  f32x4  __attribute__((ext_vector_type(4)));
typedef __bf16 bf16x8 __attribute__((ext_vector_type(8)));
typedef short  short8v __attribute__((ext_vector_type(8)));

__device__ __forceinline__ short f2bf(float f) {
  unsigned u = __float_as_uint(f);
  unsigned r = (u + 0x7FFFu + ((u >> 16) & 1u)) >> 16;  // RNE
  return (short)r;
}

__device__ __forceinline__ f32x4 mfma16(bf16x8 a, bf16x8 b, f32x4 c) {
  return __builtin_amdgcn_mfma_f32_16x16x32_bf16(a, b, c, 0, 0, 0);
}

// async global->LDS, 16B per lane. lds base must be wave-uniform; HW adds lane*16.
__device__ __forceinline__ void gload16(const void* g, void* l) {
  __builtin_amdgcn_global_load_lds(
      (const __attribute__((address_space(1))) unsigned int*)g,
      (__attribute__((address_space(3))) unsigned int*)l,
      16, 0, 0);
}

// ---------------- problem constants ----------------
// B=2, T1=T2=2048, D_MODEL=1024, N_HEAD=16, D_HEAD=64

// ---------------- conversion kernels ----------------
__global__ __launch_bounds__(256) void cvt_copy(const float* __restrict__ in,
                                                short* __restrict__ out, int n4) {
  int i = blockIdx.x * blockDim.x + threadIdx.x;
  int stride = gridDim.x * blockDim.x;
  for (; i < n4; i += stride) {
    float4 v = *(const float4*)&in[i * 4];
    short4 o;
    o.x = f2bf(v.x); o.y = f2bf(v.y); o.z = f2bf(v.z); o.w = f2bf(v.w);
    *(short4*)&out[i * 4] = o;
  }
}

// W [1024][1024] f32 (row=k, col=n)  ->  Wt [1024][1024] bf16 (row=n, col=k)
__global__ __launch_bounds__(256) void cvt_transpose(const float* __restrict__ W,
                                                     short* __restrict__ Wt) {
  __shared__ short t_s[64][72];
  int k0 = blockIdx.y * 64, n0 = blockIdx.x * 64;
  int tid = threadIdx.x;
#pragma unroll
  for (int i = 0; i < 4; i++) {
    int idx = i * 256 + tid;          // 0..1023  (64 k-rows x 16 float4 groups)
    int r = idx >> 4, cg = idx & 15;  // r = k-row within tile, cg*4 = n within tile
    float4 v = *(const float4*)&W[(k0 + r) * 1024 + n0 + cg * 4];
    t_s[cg * 4 + 0][r] = f2bf(v.x);
    t_s[cg * 4 + 1][r] = f2bf(v.y);
    t_s[cg * 4 + 2][r] = f2bf(v.z);
    t_s[cg * 4 + 3][r] = f2bf(v.w);
  }
  __syncthreads();
  // 64 n-rows x 8 short8 groups = 512 writes = 2 x 256  (was i<4: OOB + clobber bug)
#pragma unroll
  for (int i = 0; i < 2; i++) {
    int idx = i * 256 + tid;          // 0..511
    int r = idx >> 3, cg = idx & 7;   // r = n-row within tile, cg*8 = k within tile
    short8v val = *(short8v*)&t_s[r][cg * 8];
    *(short8v*)&Wt[(n0 + r) * 1024 + k0 + cg * 8] = val;
  }
}

// ---------------- GEMM: C[M=4096][N=1024] = A[4096][1024] @ Bt^T ----------------
// A row-major [M][K] bf16, Bt [N][K] bf16 (pre-transposed weights).
// EPI 0: scatter bf16 to [B,H,T,64]  (Q / K projections)
// EPI 1: scatter bf16 to [B,H,64,T]  (V projection, transposed for PV)
// EPI 2: f32 out [row][col] + b_out  (final projection)
template <int EPI>
__global__ __launch_bounds__(256) void gemm_bf16(const short* __restrict__ A,
                                                 const short* __restrict__ Bt,
                                                 void* __restrict__ out,
                                                 const float* __restrict__ bout) {
  constexpr int KD = 1024;
  __shared__ short a_s[128][64];
  __shared__ short b_s[128][64];
  int tid = threadIdx.x, w = tid >> 6, lane = tid & 63;
  int g = lane >> 4, c16 = lane & 15;
  int r0 = blockIdx.y * 128, c0 = blockIdx.x * 128;
  int wr = (w >> 1) * 64, wc = (w & 1) * 64;
  f32x4 acc[4][4] = {};

  for (int kt = 0; kt < KD / 64; ++kt) {
    int k0 = kt * 64;
    __syncthreads();  // previous compute done before overwrite
#pragma unroll
    for (int i = 0; i < 4; i++) {
      int cb = i * 256 + w * 64;  // wave-uniform chunk base
      int c = cb + lane;
      int row = c >> 3, kg = c & 7;
      gload16(A + (r0 + row) * KD + k0 + kg * 8, (char*)a_s + cb * 16);
      gload16(Bt + (c0 + row) * KD + k0 + kg * 8, (char*)b_s + cb * 16);
    }
    __syncthreads();  // staged tiles visible (barrier drains vmcnt)
#pragma unroll
    for (int kk = 0; kk < 2; kk++) {
      bf16x8 af[4], bf[4];
#pragma unroll
      for (int m = 0; m < 4; m++) af[m] = *(const bf16x8*)&a_s[wr + m * 16 + c16][kk * 32 + g * 8];
#pragma unroll
      for (int n = 0; n < 4; n++) bf[n] = *(const bf16x8*)&b_s[wc + n * 16 + c16][kk * 32 + g * 8];
#pragma unroll
      for (int m = 0; m < 4; m++)
#pragma unroll
        for (int n = 0; n < 4; n++) acc[m][n] = mfma16(af[m], bf[n], acc[m][n]);
    }
  }

#pragma unroll
  for (int m = 0; m < 4; m++)
#pragma unroll
    for (int n = 0; n < 4; n++)
#pragma unroll
      for (int r = 0; r < 4; r++) {
        int row = r0 + wr + m * 16 + g * 4 + r;  // C/D: row=(lane>>4)*4+reg
        int col = c0 + wc + n * 16 + c16;        //      col=lane&15
        float v = acc[m][n][r];
        if (EPI == 2) {
          ((float*)out)[row * 1024 + col] = v + bout[col];
        } else {
          int b = row >> 11, t = row & 2047, h = col >> 6, d = col & 63;
          short bv = f2bf(v);
          if (EPI == 0)
            ((short*)out)[(((b * 16 + h) * 2048) + t) * 64 + d] = bv;
          else
            ((short*)out)[(((b * 16 + h) * 64) + d) * 2048 + t] = bv;
        }
      }
}

// ---------------- flash attention ----------------
// grid (T1/64, H, B); block 256 (4 waves, 16 q-rows per wave)
// Qg,Kg: [B,H,T,64] bf16 ; Vtg: [B,H,64,T2] bf16 ; bias [2048][2048] f32
// Og: [B,T1,1024] bf16
__global__ __launch_bounds__(256) void flash_attn(const short* __restrict__ Qg,
                                                  const short* __restrict__ Kg,
                                                  const short* __restrict__ Vtg,
                                                  const float* __restrict__ bias,
                                                  short* __restrict__ Og) {
  __shared__ short q_s[64][64];
  __shared__ short k_s[64][64];
  __shared__ short v_s[64][64];      // V^T tile: [d][t]
  __shared__ short p_s[4][16][72];   // per-wave P transpose buffer (+pad; 144B rows, 16B-aligned)

  int tid = threadIdx.x, w = tid >> 6, lane = tid & 63;
  int g = lane >> 4, c16 = lane & 15;
  int qb = blockIdx.x * 64;
  int h = blockIdx.y, b = blockIdx.z;

  const short* Qh = Qg + (size_t)(b * 16 + h) * 2048 * 64;
  const short* Kh = Kg + (size_t)(b * 16 + h) * 2048 * 64;
  const short* Vh = Vtg + (size_t)(b * 16 + h) * 64 * 2048;
  float hs = exp2f(-(float)(h + 1));

  // stage Q block (contiguous 8KB)
#pragma unroll
  for (int i = 0; i < 2; i++) {
    int cb = i * 256 + w * 64;
    gload16(Qh + qb * 64 + (cb + lane) * 8, (char*)q_s + cb * 16);
  }

  float m_prev[4] = {-3.0e38f, -3.0e38f, -3.0e38f, -3.0e38f};
  float l_run[4] = {0.f, 0.f, 0.f, 0.f};
  f32x4 o_acc[4] = {};  // [d-tile], rows = g*4+reg, col = dt*16+c16

  for (int kt = 0; kt < 32; ++kt) {
    int kb = kt * 64;
    __syncthreads();  // prev compute done (and Q ready on iter 0)
#pragma unroll
    for (int i = 0; i < 2; i++) {
      int cb = i * 256 + w * 64;
      gload16(Kh + kb * 64 + (cb + lane) * 8, (char*)k_s + cb * 16);
      int c = cb + lane;
      int d = c >> 3, tg = c & 7;
      gload16(Vh + d * 2048 + kb + tg * 8, (char*)v_s + cb * 16);
    }
    __syncthreads();  // K,V staged

    // ---- S = Q K^T (per wave: 16 q-rows x 64 k-cols) ----
    f32x4 sacc[4] = {};
    bf16x8 aq0 = *(const bf16x8*)&q_s[w * 16 + c16][g * 8];
    bf16x8 aq1 = *(const bf16x8*)&q_s[w * 16 + c16][32 + g * 8];
#pragma unroll
    for (int ct = 0; ct < 4; ct++) {
      bf16x8 kb0 = *(const bf16x8*)&k_s[ct * 16 + c16][g * 8];
      bf16x8 kb1 = *(const bf16x8*)&k_s[ct * 16 + c16][32 + g * 8];
      sacc[ct] = mfma16(aq0, kb0, sacc[ct]);
      sacc[ct] = mfma16(aq1, kb1, sacc[ct]);
    }

    // ---- scale + bias, online softmax ----
    float s[4][4];
#pragma unroll
    for (int ct = 0; ct < 4; ct++)
#pragma unroll
      for (int r = 0; r < 4; r++) {
        int qrow = qb + w * 16 + g * 4 + r;
        int kcol = kb + ct * 16 + c16;
        s[ct][r] = sacc[ct][r] * 0.125f + bias[qrow * 2048 + kcol] * hs;
      }

#pragma unroll
    for (int r = 0; r < 4; r++) {
      float mx = fmaxf(fmaxf(s[0][r], s[1][r]), fmaxf(s[2][r], s[3][r]));
#pragma unroll
      for (int off = 1; off < 16; off <<= 1) mx = fmaxf(mx, __shfl_xor(mx, off));
      float mn = fmaxf(m_prev[r], mx);
      float al = __expf(m_prev[r] - mn);
      float psum = 0.f;
#pragma unroll
      for (int ct = 0; ct < 4; ct++) {
        float pv = __expf(s[ct][r] - mn);
        s[ct][r] = pv;
        psum += pv;
      }
#pragma unroll
      for (int off = 1; off < 16; off <<= 1) psum += __shfl_xor(psum, off);
      l_run[r] = l_run[r] * al + psum;
      m_prev[r] = mn;
#pragma unroll
      for (int dt = 0; dt < 4; dt++) o_acc[dt][r] *= al;
      // write P row to per-wave LDS (transpose to A-fragment layout)
#pragma unroll
      for (int ct = 0; ct < 4; ct++) p_s[w][g * 4 + r][ct * 16 + c16] = f2bf(s[ct][r]);
    }

    // ---- O += P @ V ----
#pragma unroll
    for (int kk = 0; kk < 2; kk++) {
      bf16x8 pa = *(const bf16x8*)&p_s[w][c16][kk * 32 + g * 8];
#pragma unroll
      for (int dt = 0; dt < 4; dt++) {
        bf16x8 vb = *(const bf16x8*)&v_s[dt * 16 + c16][kk * 32 + g * 8];
        o_acc[dt] = mfma16(pa, vb, o_acc[dt]);
      }
    }
  }

  // ---- normalize + store O (bf16, [B,T1,H*64]) ----
#pragma unroll
  for (int dt = 0; dt < 4; dt++)
#pragma unroll
    for (int r = 0; r < 4; r++) {
      int t = qb + w * 16 + g * 4 + r;
      int dcol = dt * 16 + c16;
      float ov = o_acc[dt][r] / l_run[r];
      Og[(size_t)(b * 2048 + t) * 1024 + h * 64 + dcol] = f2bf(ov);
    }
}

// ---------------- launcher ----------------
extern "C" void kernel_launch(void* const* d_in, const int* in_sizes, int n_in,
                              void* d_out, int out_size, void* d_ws, size_t ws_size,
                              hipStream_t stream) {
  const float* x    = (const float*)d_in[0];
  const float* ctx  = (const float*)d_in[1];
  const float* bias = (const float*)d_in[2];
  const float* Wq   = (const float*)d_in[3];
  const float* Wk   = (const float*)d_in[4];
  const float* Wv   = (const float*)d_in[5];
  const float* Wo   = (const float*)d_in[6];
  const float* bo   = (const float*)d_in[7];
  float* out = (float*)d_out;

  char* ws = (char*)d_ws;
  short* x_bf = (short*)(ws + 0);          // 8 MB  (4096x1024 bf16)
  short* c_bf = (short*)(ws + 8388608);    // 8 MB
  short* wq_t = (short*)(ws + 16777216);   // 2 MB  [N][K]
  short* wk_t = (short*)(ws + 18874368);   // 2 MB
  short* wv_t = (short*)(ws + 20971520);   // 2 MB
  short* wo_t = (short*)(ws + 23068672);   // 2 MB
  short* q_ws = (short*)(ws + 25165824);   // 8 MB  [B,H,T1,64]
  short* k_ws = (short*)(ws + 33554432);   // 8 MB  [B,H,T2,64]
  short* v_ws = (short*)(ws + 41943040);   // 8 MB  [B,H,64,T2]
  short* o_ws = (short*)(ws + 50331648);   // 8 MB  [B,T1,1024]

  cvt_copy<<<1024, 256, 0, stream>>>(x, x_bf, 1048576);
  cvt_copy<<<1024, 256, 0, stream>>>(ctx, c_bf, 1048576);
  dim3 tg(16, 16);
  cvt_transpose<<<tg, 256, 0, stream>>>(Wq, wq_t);
  cvt_transpose<<<tg, 256, 0, stream>>>(Wk, wk_t);
  cvt_transpose<<<tg, 256, 0, stream>>>(Wv, wv_t);
  cvt_transpose<<<tg, 256, 0, stream>>>(Wo, wo_t);

  dim3 gg(8, 32);  // (N/128, M/128)
  gemm_bf16<0><<<gg, 256, 0, stream>>>(x_bf, wq_t, q_ws, nullptr);
  gemm_bf16<0><<<gg, 256, 0, stream>>>(c_bf, wk_t, k_ws, nullptr);
  gemm_bf16<1><<<gg, 256, 0, stream>>>(c_bf, wv_t, v_ws, nullptr);

  dim3 fg(32, 16, 2);
  flash_attn<<<fg, 256, 0, stream>>>(q_ws, k_ws, v_ws, bias, o_ws);

  gemm_bf16<2><<<gg, 256, 0, stream>>>(o_ws, wo_t, out, bo);
}

// Round 3
// 216.962 us; speedup vs baseline: 1.3072x; 1.3072x over previous
//
#include <hip/hip_runtime.h>

// ---------------- types / helpers ----------------
typedef float  f32x4  __attribute__((ext_vector_type(4)));
typedef __bf16 bf16x8 __attribute__((ext_vector_type(8)));
typedef __bf16 bf16x4 __attribute__((ext_vector_type(4)));
typedef short  short8v __attribute__((ext_vector_type(8)));

__device__ __forceinline__ short f2bf(float f) {
  unsigned u = __float_as_uint(f);
  unsigned r = (u + 0x7FFFu + ((u >> 16) & 1u)) >> 16;  // RNE
  return (short)r;
}

__device__ __forceinline__ f32x4 mfma16(bf16x8 a, bf16x8 b, f32x4 c) {
  return __builtin_amdgcn_mfma_f32_16x16x32_bf16(a, b, c, 0, 0, 0);
}

// async global->LDS, 16B per lane. lds base must be wave-uniform; HW adds lane*16.
__device__ __forceinline__ void gload16(const void* g, void* l) {
  __builtin_amdgcn_global_load_lds(
      (const __attribute__((address_space(1))) unsigned int*)g,
      (__attribute__((address_space(3))) unsigned int*)l,
      16, 0, 0);
}

// ---------------- problem constants ----------------
// B=2, T1=T2=2048, D_MODEL=1024, N_HEAD=16, D_HEAD=64

// ---------------- conversion kernels ----------------
__global__ __launch_bounds__(256) void cvt_copy(const float* __restrict__ in,
                                                short* __restrict__ out, int n4) {
  int i = blockIdx.x * blockDim.x + threadIdx.x;
  int stride = gridDim.x * blockDim.x;
  for (; i < n4; i += stride) {
    float4 v = *(const float4*)&in[i * 4];
    short4 o;
    o.x = f2bf(v.x); o.y = f2bf(v.y); o.z = f2bf(v.z); o.w = f2bf(v.w);
    *(short4*)&out[i * 4] = o;
  }
}

// W [1024][1024] f32 (row=k, col=n)  ->  Wt [1024][1024] bf16 (row=n, col=k)
__global__ __launch_bounds__(256) void cvt_transpose(const float* __restrict__ W,
                                                     short* __restrict__ Wt) {
  __shared__ short t_s[64][72];
  int k0 = blockIdx.y * 64, n0 = blockIdx.x * 64;
  int tid = threadIdx.x;
#pragma unroll
  for (int i = 0; i < 4; i++) {
    int idx = i * 256 + tid;          // 0..1023  (64 k-rows x 16 float4 groups)
    int r = idx >> 4, cg = idx & 15;  // r = k-row within tile, cg*4 = n within tile
    float4 v = *(const float4*)&W[(k0 + r) * 1024 + n0 + cg * 4];
    t_s[cg * 4 + 0][r] = f2bf(v.x);
    t_s[cg * 4 + 1][r] = f2bf(v.y);
    t_s[cg * 4 + 2][r] = f2bf(v.z);
    t_s[cg * 4 + 3][r] = f2bf(v.w);
  }
  __syncthreads();
  // 64 n-rows x 8 short8 groups = 512 writes = 2 x 256
#pragma unroll
  for (int i = 0; i < 2; i++) {
    int idx = i * 256 + tid;          // 0..511
    int r = idx >> 3, cg = idx & 7;   // r = n-row within tile, cg*8 = k within tile
    short8v val = *(short8v*)&t_s[r][cg * 8];
    *(short8v*)&Wt[(n0 + r) * 1024 + k0 + cg * 8] = val;
  }
}

// ---------------- GEMM: C[M=4096][N=1024] = A[4096][1024] @ Bt^T ----------------
template <int EPI>
__global__ __launch_bounds__(256) void gemm_bf16(const short* __restrict__ A,
                                                 const short* __restrict__ Bt,
                                                 void* __restrict__ out,
                                                 const float* __restrict__ bout) {
  constexpr int KD = 1024;
  __shared__ short a_s[128][64];
  __shared__ short b_s[128][64];
  int tid = threadIdx.x, w = tid >> 6, lane = tid & 63;
  int g = lane >> 4, c16 = lane & 15;
  int r0 = blockIdx.y * 128, c0 = blockIdx.x * 128;
  int wr = (w >> 1) * 64, wc = (w & 1) * 64;
  f32x4 acc[4][4] = {};

  for (int kt = 0; kt < KD / 64; ++kt) {
    int k0 = kt * 64;
    __syncthreads();
#pragma unroll
    for (int i = 0; i < 4; i++) {
      int cb = i * 256 + w * 64;  // wave-uniform chunk base
      int c = cb + lane;
      int row = c >> 3, kg = c & 7;
      gload16(A + (r0 + row) * KD + k0 + kg * 8, (char*)a_s + cb * 16);
      gload16(Bt + (c0 + row) * KD + k0 + kg * 8, (char*)b_s + cb * 16);
    }
    __syncthreads();
#pragma unroll
    for (int kk = 0; kk < 2; kk++) {
      bf16x8 af[4], bf[4];
#pragma unroll
      for (int m = 0; m < 4; m++) af[m] = *(const bf16x8*)&a_s[wr + m * 16 + c16][kk * 32 + g * 8];
#pragma unroll
      for (int n = 0; n < 4; n++) bf[n] = *(const bf16x8*)&b_s[wc + n * 16 + c16][kk * 32 + g * 8];
#pragma unroll
      for (int m = 0; m < 4; m++)
#pragma unroll
        for (int n = 0; n < 4; n++) acc[m][n] = mfma16(af[m], bf[n], acc[m][n]);
    }
  }

#pragma unroll
  for (int m = 0; m < 4; m++)
#pragma unroll
    for (int n = 0; n < 4; n++)
#pragma unroll
      for (int r = 0; r < 4; r++) {
        int row = r0 + wr + m * 16 + g * 4 + r;  // C/D: row=(lane>>4)*4+reg
        int col = c0 + wc + n * 16 + c16;        //      col=lane&15
        float v = acc[m][n][r];
        if (EPI == 2) {
          ((float*)out)[row * 1024 + col] = v + bout[col];
        } else {
          int b = row >> 11, t = row & 2047, h = col >> 6, d = col & 63;
          short bv = f2bf(v);
          if (EPI == 0)
            ((short*)out)[(((b * 16 + h) * 2048) + t) * 64 + d] = bv;
          else
            ((short*)out)[(((b * 16 + h) * 64) + d) * 2048 + t] = bv;
        }
      }
}

// ---------------- flash attention v2 ----------------
// Swapped QK^T (S[k][q] via mfma(K,Q)) -> per-lane in-register softmax, no
// max-subtraction (|s| bounded ~8; exp2-domain), XOR-swizzled LDS (T2),
// Q in registers, double-buffered K/V with counted vmcnt + raw barriers.
// grid (T1/64, H, B); block 256 (4 waves, 16 q-rows per wave)
__global__ __launch_bounds__(256, 4) void flash_attn(const short* __restrict__ Qg,
                                                     const short* __restrict__ Kg,
                                                     const short* __restrict__ Vtg,
                                                     const float* __restrict__ bias,
                                                     short* __restrict__ Og) {
  __shared__ short k_s[2][64][64];   // [buf][k-row][d]   (16B-slot XOR-swizzled by row&7)
  __shared__ short v_s[2][64][64];   // [buf][d][t]       (16B-slot XOR-swizzled by row&7)
  __shared__ short p_s[4][16][64];   // per-wave P [q][k] (16B-slot XOR-swizzled by q&7)

  int tid = threadIdx.x, w = tid >> 6, lane = tid & 63;
  int g = lane >> 4, c16 = lane & 15;
  int qb = blockIdx.x * 64;
  int h = blockIdx.y, b = blockIdx.z;

  const short* Qh = Qg + (size_t)(b * 16 + h) * 2048 * 64;
  const short* Kh = Kg + (size_t)(b * 16 + h) * 2048 * 64;
  const short* Vh = Vtg + (size_t)(b * 16 + h) * 64 * 2048;

  const float C1 = 0.125f * 1.44269504f;                 // atten_scale * log2(e)
  const float C2 = exp2f(-(float)(h + 1)) * 1.44269504f; // head_scale * log2(e)

  int qrow = qb + w * 16 + c16;
  const float* bp = bias + (size_t)qrow * 2048 + 4 * g;

  // ---- prologue: stage tile 0, load Q fragment to registers ----
#pragma unroll
  for (int i = 0; i < 2; i++) {
    int cb = i * 256 + w * 64;
    int c = cb + lane;
    int row = c >> 3, t8 = c & 7, sw = (t8 ^ (row & 7)) * 8;  // inverse-swizzled source
    gload16(Kh + row * 64 + sw, (char*)&k_s[0][0][0] + cb * 16);
    gload16(Vh + row * 2048 + sw, (char*)&v_s[0][0][0] + cb * 16);
  }
  bf16x8 qreg0 = *(const bf16x8*)(Qh + (size_t)qrow * 64 + g * 8);       // d = g*8..+7
  bf16x8 qreg1 = *(const bf16x8*)(Qh + (size_t)qrow * 64 + 32 + g * 8);  // d = 32+g*8..

  float l_run = 0.f;
  f32x4 o_acc[4] = {};        // rows q=4g+r, cols d = dt*16+c16
  const int hsw = c16 & 7;    // row-XOR swizzle key (all our LDS rows have row&7 == c16&7)
  const int s0 = g ^ hsw;     // physical 16B-slot for logical slot g (kk=0)

  for (int kt = 0; kt < 32; ++kt) {
    int cur = kt & 1;
    // bias loads for this tile (issued early; 4 newest vmem before stage)
    float4 bv0 = *(const float4*)(bp + 0);
    float4 bv1 = *(const float4*)(bp + 16);
    float4 bv2 = *(const float4*)(bp + 32);
    float4 bv3 = *(const float4*)(bp + 48);
    bp += 64;

    if (kt < 31) {
      // stage next tile into other buffer
      const short* Ks = Kh + (size_t)(kt + 1) * 64 * 64;
      const short* Vs = Vh + (kt + 1) * 64;
      char* kd = (char*)&k_s[cur ^ 1][0][0];
      char* vd = (char*)&v_s[cur ^ 1][0][0];
#pragma unroll
      for (int i = 0; i < 2; i++) {
        int cb = i * 256 + w * 64;
        int c = cb + lane;
        int row = c >> 3, t8 = c & 7, sw = (t8 ^ (row & 7)) * 8;
        gload16(Ks + row * 64 + sw, kd + cb * 16);
        gload16(Vs + row * 2048 + sw, vd + cb * 16);
      }
      // wait: current tile's 4 stage loads done (8 newer: 4 bias + 4 next-stage)
      asm volatile("s_waitcnt vmcnt(8)" ::: "memory");
    } else {
      asm volatile("s_waitcnt vmcnt(4)" ::: "memory");  // only 4 bias newer
    }
    __builtin_amdgcn_s_barrier();  // (a) current buffer staged on all waves

    // ---- S[k][q] = K . Q  (A = K rows, B = Q rows) ----
    f32x4 sacc[4] = {};
#pragma unroll
    for (int t = 0; t < 4; t++) {
      const short* kr = &k_s[cur][t * 16 + c16][0];
      bf16x8 kf0 = *(const bf16x8*)(kr + s0 * 8);          // logical slot g
      bf16x8 kf1 = *(const bf16x8*)(kr + (s0 ^ 4) * 8);    // logical slot 4+g
      sacc[t] = mfma16(kf0, qreg0, sacc[t]);
      sacc[t] = mfma16(kf1, qreg1, sacc[t]);
    }

    // ---- softmax numerator (exp2-domain, no max subtraction) ----
    // lane holds S[kb+16t+4g+r][qrow]; bias[qrow][kb+16t+4g+r] = bv_t[r]
    float lp = 0.f;
#pragma unroll
    for (int t = 0; t < 4; t++) {
      float4 bv = (t == 0) ? bv0 : (t == 1) ? bv1 : (t == 2) ? bv2 : bv3;
      float p0 = exp2f(sacc[t][0] * C1 + bv.x * C2);
      float p1 = exp2f(sacc[t][1] * C1 + bv.y * C2);
      float p2 = exp2f(sacc[t][2] * C1 + bv.z * C2);
      float p3 = exp2f(sacc[t][3] * C1 + bv.w * C2);
      lp += (p0 + p1) + (p2 + p3);
      bf16x4 pk = {(__bf16)p0, (__bf16)p1, (__bf16)p2, (__bf16)p3};
      int sl = (2 * t + (g >> 1)) ^ hsw;                       // swizzled 16B slot
      *(bf16x4*)&p_s[w][c16][sl * 8 + (g & 1) * 4] = pk;       // k = 16t+4g+0..3
    }
    l_run += lp;

    // ---- O += P @ V  (A = P rows q, B = V^T rows d) ----
#pragma unroll
    for (int kk = 0; kk < 2; kk++) {
      int sp = (4 * kk + g) ^ hsw;
      bf16x8 pa = *(const bf16x8*)&p_s[w][c16][sp * 8];
#pragma unroll
      for (int dt = 0; dt < 4; dt++) {
        bf16x8 vb = *(const bf16x8*)&v_s[cur][dt * 16 + c16][sp * 8];
        o_acc[dt] = mfma16(pa, vb, o_acc[dt]);
      }
    }
    __builtin_amdgcn_s_barrier();  // (b) all waves done reading cur before overwrite
  }

  // ---- final l reduction (lanes c16, c16+16, c16+32, c16+48 share q=c16) ----
  l_run += __shfl_xor(l_run, 16);
  l_run += __shfl_xor(l_run, 32);
  float inv[4];
#pragma unroll
  for (int r = 0; r < 4; r++) inv[r] = 1.f / __shfl(l_run, 4 * g + r);

  // ---- store O (bf16, [B,T1,H*64]); o_acc row = q=4g+r, col d=dt*16+c16 ----
#pragma unroll
  for (int dt = 0; dt < 4; dt++)
#pragma unroll
    for (int r = 0; r < 4; r++) {
      int t = qb + w * 16 + 4 * g + r;
      Og[(size_t)(b * 2048 + t) * 1024 + h * 64 + dt * 16 + c16] =
          f2bf(o_acc[dt][r] * inv[r]);
    }
}

// ---------------- launcher ----------------
extern "C" void kernel_launch(void* const* d_in, const int* in_sizes, int n_in,
                              void* d_out, int out_size, void* d_ws, size_t ws_size,
                              hipStream_t stream) {
  const float* x    = (const float*)d_in[0];
  const float* ctx  = (const float*)d_in[1];
  const float* bias = (const float*)d_in[2];
  const float* Wq   = (const float*)d_in[3];
  const float* Wk   = (const float*)d_in[4];
  const float* Wv   = (const float*)d_in[5];
  const float* Wo   = (const float*)d_in[6];
  const float* bo   = (const float*)d_in[7];
  float* out = (float*)d_out;

  char* ws = (char*)d_ws;
  short* x_bf = (short*)(ws + 0);          // 8 MB  (4096x1024 bf16)
  short* c_bf = (short*)(ws + 8388608);    // 8 MB
  short* wq_t = (short*)(ws + 16777216);   // 2 MB  [N][K]
  short* wk_t = (short*)(ws + 18874368);   // 2 MB
  short* wv_t = (short*)(ws + 20971520);   // 2 MB
  short* wo_t = (short*)(ws + 23068672);   // 2 MB
  short* q_ws = (short*)(ws + 25165824);   // 8 MB  [B,H,T1,64]
  short* k_ws = (short*)(ws + 33554432);   // 8 MB  [B,H,T2,64]
  short* v_ws = (short*)(ws + 41943040);   // 8 MB  [B,H,64,T2]
  short* o_ws = (short*)(ws + 50331648);   // 8 MB  [B,T1,1024]

  cvt_copy<<<1024, 256, 0, stream>>>(x, x_bf, 1048576);
  cvt_copy<<<1024, 256, 0, stream>>>(ctx, c_bf, 1048576);
  dim3 tg(16, 16);
  cvt_transpose<<<tg, 256, 0, stream>>>(Wq, wq_t);
  cvt_transpose<<<tg, 256, 0, stream>>>(Wk, wk_t);
  cvt_transpose<<<tg, 256, 0, stream>>>(Wv, wv_t);
  cvt_transpose<<<tg, 256, 0, stream>>>(Wo, wo_t);

  dim3 gg(8, 32);  // (N/128, M/128)
  gemm_bf16<0><<<gg, 256, 0, stream>>>(x_bf, wq_t, q_ws, nullptr);
  gemm_bf16<0><<<gg, 256, 0, stream>>>(c_bf, wk_t, k_ws, nullptr);
  gemm_bf16<1><<<gg, 256, 0, stream>>>(c_bf, wv_t, v_ws, nullptr);

  dim3 fg(32, 16, 2);
  flash_attn<<<fg, 256, 0, stream>>>(q_ws, k_ws, v_ws, bias, o_ws);

  gemm_bf16<2><<<gg, 256, 0, stream>>>(o_ws, wo_t, out, bo);
}

// Round 4
// 160.321 us; speedup vs baseline: 1.7690x; 1.3533x over previous
//
#include <hip/hip_runtime.h>

// ---------------- types / helpers ----------------
typedef float  f32x4  __attribute__((ext_vector_type(4)));
typedef __bf16 bf16x8 __attribute__((ext_vector_type(8)));
typedef __bf16 bf16x4 __attribute__((ext_vector_type(4)));
typedef short  short8v __attribute__((ext_vector_type(8)));

__device__ __forceinline__ short f2bf(float f) {
  unsigned u = __float_as_uint(f);
  unsigned r = (u + 0x7FFFu + ((u >> 16) & 1u)) >> 16;  // RNE
  return (short)r;
}

__device__ __forceinline__ f32x4 mfma16(bf16x8 a, bf16x8 b, f32x4 c) {
  return __builtin_amdgcn_mfma_f32_16x16x32_bf16(a, b, c, 0, 0, 0);
}

// async global->LDS, 16B per lane. lds base must be wave-uniform; HW adds lane*16.
__device__ __forceinline__ void gload16(const void* g, void* l) {
  __builtin_amdgcn_global_load_lds(
      (const __attribute__((address_space(1))) unsigned int*)g,
      (__attribute__((address_space(3))) unsigned int*)l,
      16, 0, 0);
}

// ---------------- problem constants ----------------
// B=2, T1=T2=2048, D_MODEL=1024, N_HEAD=16, D_HEAD=64

// ---------------- conversion kernels ----------------
__global__ __launch_bounds__(256) void cvt_copy(const float* __restrict__ in,
                                                short* __restrict__ out, int n4) {
  int i = blockIdx.x * blockDim.x + threadIdx.x;
  int stride = gridDim.x * blockDim.x;
  for (; i < n4; i += stride) {
    float4 v = *(const float4*)&in[i * 4];
    short4 o;
    o.x = f2bf(v.x); o.y = f2bf(v.y); o.z = f2bf(v.z); o.w = f2bf(v.w);
    *(short4*)&out[i * 4] = o;
  }
}

// W [1024][1024] f32 (row=k, col=n)  ->  Wt [1024][1024] bf16 (row=n, col=k)
__global__ __launch_bounds__(256) void cvt_transpose(const float* __restrict__ W,
                                                     short* __restrict__ Wt) {
  __shared__ short t_s[64][72];
  int k0 = blockIdx.y * 64, n0 = blockIdx.x * 64;
  int tid = threadIdx.x;
#pragma unroll
  for (int i = 0; i < 4; i++) {
    int idx = i * 256 + tid;          // 0..1023  (64 k-rows x 16 float4 groups)
    int r = idx >> 4, cg = idx & 15;
    float4 v = *(const float4*)&W[(k0 + r) * 1024 + n0 + cg * 4];
    t_s[cg * 4 + 0][r] = f2bf(v.x);
    t_s[cg * 4 + 1][r] = f2bf(v.y);
    t_s[cg * 4 + 2][r] = f2bf(v.z);
    t_s[cg * 4 + 3][r] = f2bf(v.w);
  }
  __syncthreads();
#pragma unroll
  for (int i = 0; i < 2; i++) {
    int idx = i * 256 + tid;          // 0..511
    int r = idx >> 3, cg = idx & 7;
    short8v val = *(short8v*)&t_s[r][cg * 8];
    *(short8v*)&Wt[(n0 + r) * 1024 + k0 + cg * 8] = val;
  }
}

// ---------------- GEMM: C[M=4096][N=1024] = A[4096][1024] @ Bt^T ----------------
// 64x64 tiles (1024 blocks -> 4 blocks/CU, 16 waves/CU) + T2 XOR-swizzled LDS
// + XCD-aware block swizzle.
template <int EPI>
__global__ __launch_bounds__(256, 4) void gemm_bf16(const short* __restrict__ A,
                                                    const short* __restrict__ Bt,
                                                    void* __restrict__ out,
                                                    const float* __restrict__ bout) {
  constexpr int KD = 1024;
  __shared__ short a_s[64][64];
  __shared__ short b_s[64][64];
  int tid = threadIdx.x, w = tid >> 6, lane = tid & 63;
  int g = lane >> 4, c16 = lane & 15;
  int hsw = c16 & 7;

  // XCD swizzle: 1024 blocks -> contiguous chunks of 128 per XCD
  int lin = blockIdx.x + 16 * blockIdx.y;           // grid (16, 64)
  int wk = (lin & 7) * 128 + (lin >> 3);
  int c0 = (wk & 15) * 64, r0 = (wk >> 4) * 64;

  int wr = (w >> 1) * 32, wc = (w & 1) * 32;
  f32x4 acc[2][2] = {};

  for (int kt = 0; kt < KD / 64; ++kt) {
    int k0 = kt * 64;
    __syncthreads();
#pragma unroll
    for (int i = 0; i < 2; i++) {
      int cb = i * 256 + w * 64;  // wave-uniform chunk base
      int c = cb + lane;
      int row = c >> 3, kg = c & 7;
      int sw = (kg ^ (row & 7)) * 8;   // pre-swizzled source col
      gload16(A + (r0 + row) * KD + k0 + sw, (char*)a_s + cb * 16);
      gload16(Bt + (c0 + row) * KD + k0 + sw, (char*)b_s + cb * 16);
    }
    __syncthreads();
#pragma unroll
    for (int kk = 0; kk < 2; kk++) {
      bf16x8 af[2], bf[2];
      int sl0 = ((4 * kk + g) ^ hsw) * 8;   // swizzled 16B slot (short offset)
#pragma unroll
      for (int m = 0; m < 2; m++) af[m] = *(const bf16x8*)&a_s[wr + m * 16 + c16][sl0];
#pragma unroll
      for (int n = 0; n < 2; n++) bf[n] = *(const bf16x8*)&b_s[wc + n * 16 + c16][sl0];
#pragma unroll
      for (int m = 0; m < 2; m++)
#pragma unroll
        for (int n = 0; n < 2; n++) acc[m][n] = mfma16(af[m], bf[n], acc[m][n]);
    }
  }

#pragma unroll
  for (int m = 0; m < 2; m++)
#pragma unroll
    for (int n = 0; n < 2; n++)
#pragma unroll
      for (int r = 0; r < 4; r++) {
        int row = r0 + wr + m * 16 + g * 4 + r;  // C/D: row=(lane>>4)*4+reg
        int col = c0 + wc + n * 16 + c16;        //      col=lane&15
        float v = acc[m][n][r];
        if (EPI == 2) {
          ((float*)out)[row * 1024 + col] = v + bout[col];
        } else {
          int b = row >> 11, t = row & 2047, h = col >> 6, d = col & 63;
          short bv = f2bf(v);
          if (EPI == 0)
            ((short*)out)[(((b * 16 + h) * 2048) + t) * 64 + d] = bv;
          else
            ((short*)out)[(((b * 16 + h) * 64) + d) * 2048 + t] = bv;
        }
      }
}

// ---------------- flash attention v3 ----------------
// 8 waves, QBLK=128 (wave w owns q-rows qb+w*16..+15), KVBLK=64.
// Swapped QK^T -> in-register softmax (exp2-domain, no max subtraction),
// XOR-swizzled K/V/P LDS, double-buffered K/V, counted vmcnt, setprio,
// XCD-aware block swizzle.
__global__ __launch_bounds__(512, 4) void flash_attn(const short* __restrict__ Qg,
                                                     const short* __restrict__ Kg,
                                                     const short* __restrict__ Vtg,
                                                     const float* __restrict__ bias,
                                                     short* __restrict__ Og) {
  __shared__ short k_s[2][64][64];   // [buf][k-row][d]  (16B-slot XOR-swizzled by row&7)
  __shared__ short v_s[2][64][64];   // [buf][d][t]      (16B-slot XOR-swizzled by row&7)
  __shared__ short p_s[8][16][64];   // per-wave P [q][k] (swizzled by q&7)

  int tid = threadIdx.x, w = tid >> 6, lane = tid & 63;
  int g = lane >> 4, c16 = lane & 15;

  // XCD swizzle: 512 blocks -> 64-chunks per XCD (4 heads' K/V pinned per L2)
  int lin = blockIdx.x + 16 * (blockIdx.y + 16 * blockIdx.z);  // grid (16,16,2)
  int wk = (lin & 7) * 64 + (lin >> 3);
  int qb = (wk & 15) * 128;
  int h = (wk >> 4) & 15;
  int b = wk >> 8;

  const short* Qh = Qg + (size_t)(b * 16 + h) * 2048 * 64;
  const short* Kh = Kg + (size_t)(b * 16 + h) * 2048 * 64;
  const short* Vh = Vtg + (size_t)(b * 16 + h) * 64 * 2048;

  const float C1 = 0.125f * 1.44269504f;                 // atten_scale * log2(e)
  const float C2 = exp2f(-(float)(h + 1)) * 1.44269504f; // head_scale * log2(e)

  int qrow = qb + w * 16 + c16;
  const float* bp = bias + (size_t)qrow * 2048 + 4 * g;

  // ---- prologue: stage tile 0 (1 K + 1 V chunk per thread), Q to registers ----
  {
    int row = tid >> 3, t8 = tid & 7, sw = (t8 ^ (row & 7)) * 8;
    gload16(Kh + row * 64 + sw, (char*)&k_s[0][0][0] + (w * 64) * 16);
    gload16(Vh + row * 2048 + sw, (char*)&v_s[0][0][0] + (w * 64) * 16);
  }
  bf16x8 qreg0 = *(const bf16x8*)(Qh + (size_t)qrow * 64 + g * 8);
  bf16x8 qreg1 = *(const bf16x8*)(Qh + (size_t)qrow * 64 + 32 + g * 8);
  asm volatile("" ::: "memory");  // pin issue order: prologue+Q before loop loads

  float l_run = 0.f;
  f32x4 o_acc[4] = {};        // rows q=4g+r, cols d = dt*16+c16
  const int hsw = c16 & 7;    // row-XOR swizzle key
  const int s0 = g ^ hsw;

  for (int kt = 0; kt < 32; ++kt) {
    int cur = kt & 1;
    // bias loads for this tile (in flight across the fence; counted)
    float4 bv0 = *(const float4*)(bp + 0);
    float4 bv1 = *(const float4*)(bp + 16);
    float4 bv2 = *(const float4*)(bp + 32);
    float4 bv3 = *(const float4*)(bp + 48);
    bp += 64;

    if (kt < 31) {
      const short* Ks = Kh + (size_t)(kt + 1) * 64 * 64;
      const short* Vs = Vh + (kt + 1) * 64;
      int row = tid >> 3, t8 = tid & 7, sw = (t8 ^ (row & 7)) * 8;
      gload16(Ks + row * 64 + sw, (char*)&k_s[cur ^ 1][0][0] + (w * 64) * 16);
      gload16(Vs + row * 2048 + sw, (char*)&v_s[cur ^ 1][0][0] + (w * 64) * 16);
      // outstanding: [cur-stage 2 (oldest)][bias 4][next-stage 2] = 8
      asm volatile("s_waitcnt vmcnt(6)" ::: "memory");
    } else {
      asm volatile("s_waitcnt vmcnt(4)" ::: "memory");  // [cur 2][bias 4]
    }
    __builtin_amdgcn_s_barrier();  // (a) current buffer staged on all waves

    // ---- S[k][q] = K . Q ----
    f32x4 sacc[4] = {};
    __builtin_amdgcn_s_setprio(1);
#pragma unroll
    for (int t = 0; t < 4; t++) {
      const short* kr = &k_s[cur][t * 16 + c16][0];
      bf16x8 kf0 = *(const bf16x8*)(kr + s0 * 8);
      bf16x8 kf1 = *(const bf16x8*)(kr + (s0 ^ 4) * 8);
      sacc[t] = mfma16(kf0, qreg0, sacc[t]);
      sacc[t] = mfma16(kf1, qreg1, sacc[t]);
    }
    __builtin_amdgcn_s_setprio(0);

    // ---- softmax numerator (exp2-domain, no max subtraction) ----
    float lp = 0.f;
#pragma unroll
    for (int t = 0; t < 4; t++) {
      float4 bv = (t == 0) ? bv0 : (t == 1) ? bv1 : (t == 2) ? bv2 : bv3;
      float p0 = exp2f(sacc[t][0] * C1 + bv.x * C2);
      float p1 = exp2f(sacc[t][1] * C1 + bv.y * C2);
      float p2 = exp2f(sacc[t][2] * C1 + bv.z * C2);
      float p3 = exp2f(sacc[t][3] * C1 + bv.w * C2);
      lp += (p0 + p1) + (p2 + p3);
      bf16x4 pk = {(__bf16)p0, (__bf16)p1, (__bf16)p2, (__bf16)p3};
      int sl = (2 * t + (g >> 1)) ^ hsw;
      *(bf16x4*)&p_s[w][c16][sl * 8 + (g & 1) * 4] = pk;   // k = 16t+4g+0..3
    }
    l_run += lp;

    // ---- O += P @ V ----
    __builtin_amdgcn_s_setprio(1);
#pragma unroll
    for (int kk = 0; kk < 2; kk++) {
      int sp = (4 * kk + g) ^ hsw;
      bf16x8 pa = *(const bf16x8*)&p_s[w][c16][sp * 8];
#pragma unroll
      for (int dt = 0; dt < 4; dt++) {
        bf16x8 vb = *(const bf16x8*)&v_s[cur][dt * 16 + c16][sp * 8];
        o_acc[dt] = mfma16(pa, vb, o_acc[dt]);
      }
    }
    __builtin_amdgcn_s_setprio(0);
    __builtin_amdgcn_s_barrier();  // (b) all waves done reading cur
  }

  // ---- final l reduction (lanes c16, +16, +32, +48 share q=c16) ----
  l_run += __shfl_xor(l_run, 16);
  l_run += __shfl_xor(l_run, 32);
  float inv[4];
#pragma unroll
  for (int r = 0; r < 4; r++) inv[r] = 1.f / __shfl(l_run, 4 * g + r);

  // ---- store O (bf16, [B,T1,H*64]) ----
#pragma unroll
  for (int dt = 0; dt < 4; dt++)
#pragma unroll
    for (int r = 0; r < 4; r++) {
      int t = qb + w * 16 + 4 * g + r;
      Og[(size_t)(b * 2048 + t) * 1024 + h * 64 + dt * 16 + c16] =
          f2bf(o_acc[dt][r] * inv[r]);
    }
}

// ---------------- launcher ----------------
extern "C" void kernel_launch(void* const* d_in, const int* in_sizes, int n_in,
                              void* d_out, int out_size, void* d_ws, size_t ws_size,
                              hipStream_t stream) {
  const float* x    = (const float*)d_in[0];
  const float* ctx  = (const float*)d_in[1];
  const float* bias = (const float*)d_in[2];
  const float* Wq   = (const float*)d_in[3];
  const float* Wk   = (const float*)d_in[4];
  const float* Wv   = (const float*)d_in[5];
  const float* Wo   = (const float*)d_in[6];
  const float* bo   = (const float*)d_in[7];
  float* out = (float*)d_out;

  char* ws = (char*)d_ws;
  short* x_bf = (short*)(ws + 0);          // 8 MB  (4096x1024 bf16)
  short* c_bf = (short*)(ws + 8388608);    // 8 MB
  short* wq_t = (short*)(ws + 16777216);   // 2 MB  [N][K]
  short* wk_t = (short*)(ws + 18874368);   // 2 MB
  short* wv_t = (short*)(ws + 20971520);   // 2 MB
  short* wo_t = (short*)(ws + 23068672);   // 2 MB
  short* q_ws = (short*)(ws + 25165824);   // 8 MB  [B,H,T1,64]
  short* k_ws = (short*)(ws + 33554432);   // 8 MB  [B,H,T2,64]
  short* v_ws = (short*)(ws + 41943040);   // 8 MB  [B,H,64,T2]
  short* o_ws = (short*)(ws + 50331648);   // 8 MB  [B,T1,1024]

  cvt_copy<<<1024, 256, 0, stream>>>(x, x_bf, 1048576);
  cvt_copy<<<1024, 256, 0, stream>>>(ctx, c_bf, 1048576);
  dim3 tg(16, 16);
  cvt_transpose<<<tg, 256, 0, stream>>>(Wq, wq_t);
  cvt_transpose<<<tg, 256, 0, stream>>>(Wk, wk_t);
  cvt_transpose<<<tg, 256, 0, stream>>>(Wv, wv_t);
  cvt_transpose<<<tg, 256, 0, stream>>>(Wo, wo_t);

  dim3 gg(16, 64);  // (N/64, M/64)
  gemm_bf16<0><<<gg, 256, 0, stream>>>(x_bf, wq_t, q_ws, nullptr);
  gemm_bf16<0><<<gg, 256, 0, stream>>>(c_bf, wk_t, k_ws, nullptr);
  gemm_bf16<1><<<gg, 256, 0, stream>>>(c_bf, wv_t, v_ws, nullptr);

  dim3 fg(16, 16, 2);
  flash_attn<<<fg, 512, 0, stream>>>(q_ws, k_ws, v_ws, bias, o_ws);

  gemm_bf16<2><<<gg, 256, 0, stream>>>(o_ws, wo_t, out, bo);
}